// Round 4
// baseline (396.392 us; speedup 1.0000x reference)
//
#include <hip/hip_runtime.h>

typedef _Float16 f16;
typedef _Float16 f16x4 __attribute__((ext_vector_type(4)));
typedef _Float16 f16x8 __attribute__((ext_vector_type(8)));
typedef float f32x4 __attribute__((ext_vector_type(4)));

static __device__ __forceinline__ f32x4 mfma_k32(f16x8 a, f16x8 b, f32x4 c) {
  return __builtin_amdgcn_mfma_f32_16x16x32_f16(a, b, c, 0, 0, 0);
}
static __device__ __forceinline__ f32x4 mfma_k16(f16x4 a, f16x4 b, f32x4 c) {
  return __builtin_amdgcn_mfma_f32_16x16x16f16(a, b, c, 0, 0, 0);
}

#define BN 2048    // sequence length
#define CC 512     // channels
#define NHD 64     // head dim
#define MROWS 8192 // B*N
#define SLAB ((size_t)32 * BN * NHD)  // one of Q/K/V: 4,194,304 f16

// ---------------------------------------------------------------------------
// QKV GEMM: C[m][d] = sum_k X[m][k] * Wqkv[d][k]
// M=8192, D=1536, K=512.
// Epilogue: Q (scaled 0.125) and K -> (b,h,n,hd); V -> TRANSPOSED (b,h,hd,n).
// ---------------------------------------------------------------------------
__global__ __launch_bounds__(256)
void qkv_gemm(const float* __restrict__ X, const float* __restrict__ W,
              f16* __restrict__ qkv) {
  __shared__ __align__(16) f16 As[128][40];
  __shared__ __align__(16) f16 Bs[128][40];
  const int t = threadIdx.x;
  const int lane = t & 63, wave = t >> 6;
  const int wr = wave >> 1, wc = wave & 1;
  const int mt = blockIdx.x / 12, nt = blockIdx.x % 12;
  const int m0 = mt * 128, n0 = nt * 128;
  const int grp = lane >> 4, lid = lane & 15;

  const f32x4 zf = {0.f, 0.f, 0.f, 0.f};
  f32x4 acc[4][4];
#pragma unroll
  for (int i = 0; i < 4; i++)
#pragma unroll
    for (int j = 0; j < 4; j++) acc[i][j] = zf;

  const int r = t >> 1, hh = (t & 1) * 16;
  for (int k0 = 0; k0 < CC; k0 += 32) {
    const float* sa = X + (size_t)(m0 + r) * CC + k0 + hh;
    const float* sb = W + (size_t)(n0 + r) * CC + k0 + hh;
#pragma unroll
    for (int j = 0; j < 4; j++) {
      float4 va = *(const float4*)(sa + 4 * j);
      float4 vb = *(const float4*)(sb + 4 * j);
      f16x4 fa = {(f16)va.x, (f16)va.y, (f16)va.z, (f16)va.w};
      f16x4 fb = {(f16)vb.x, (f16)vb.y, (f16)vb.z, (f16)vb.w};
      *(f16x4*)&As[r][hh + 4 * j] = fa;
      *(f16x4*)&Bs[r][hh + 4 * j] = fb;
    }
    __syncthreads();
    f16x8 af[4], bf[4];
#pragma unroll
    for (int mi = 0; mi < 4; mi++)
      af[mi] = *(const f16x8*)&As[wr * 64 + mi * 16 + lid][grp * 8];
#pragma unroll
    for (int ni = 0; ni < 4; ni++)
      bf[ni] = *(const f16x8*)&Bs[wc * 64 + ni * 16 + lid][grp * 8];
#pragma unroll
    for (int mi = 0; mi < 4; mi++)
#pragma unroll
      for (int ni = 0; ni < 4; ni++)
        acc[mi][ni] = mfma_k32(af[mi], bf[ni], acc[mi][ni]);
    __syncthreads();
  }
  // epilogue
#pragma unroll
  for (int ni = 0; ni < 4; ni++) {
    int d = n0 + wc * 64 + ni * 16 + lid;
    int s = d >> 9;
    int h = (d & 511) >> 6;
    int hd = d & 63;
    if (s == 2) {
      // V transposed: vT[((b*8+h)*64+hd)*2048 + n], vectorized 4-row store
#pragma unroll
      for (int mi = 0; mi < 4; mi++) {
        int row0 = m0 + wr * 64 + mi * 16 + grp * 4;
        int b = row0 >> 11, n = row0 & 2047;
        f16x4 pk = {(f16)acc[mi][ni][0], (f16)acc[mi][ni][1],
                    (f16)acc[mi][ni][2], (f16)acc[mi][ni][3]};
        *(f16x4*)&qkv[2 * SLAB + ((size_t)((b * 8 + h) * 64 + hd)) * BN + n] = pk;
      }
    } else {
      float scale = (s == 0) ? 0.125f : 1.0f;
#pragma unroll
      for (int mi = 0; mi < 4; mi++) {
#pragma unroll
        for (int i = 0; i < 4; i++) {
          int row = m0 + wr * 64 + mi * 16 + grp * 4 + i;
          int b = row >> 11, n = row & 2047;
          qkv[(size_t)s * SLAB + (((size_t)(b * 8 + h) * BN + n)) * NHD + hd] =
              (f16)(acc[mi][ni][i] * scale);
        }
      }
    }
  }
}

// ---------------------------------------------------------------------------
// Flash attention, LDS-free, barrier-free, register-direct.
// Grid: bid = qb*32 + bh -> XCD(bid%8) == bh%8: each head's K/V pinned to one
// XCD's L2 (4 heads x 1MB = L2-resident; round-3 FETCH confirmed 12 MB).
// Block = 64 q-rows of one (b,h); 4 waves x 16 q-rows. 1024 blocks ->
// 16 waves/CU: TLP hides the L2-hit latency (round-2 structure was
// register-clean at VGPR=68; this drops its 2nd q-tile to double wave count).
// Swapped QK^T (mfma(K,Q)): lane (qv,grp) holds S[key=kt*16+grp*4+i][q=qv]
// -> softmax P feeds PV (16x16x16 B-operand) directly from registers.
// ---------------------------------------------------------------------------
__global__ __launch_bounds__(256)
void attn(const f16* __restrict__ qkv, f16* __restrict__ O) {
  const int bh = blockIdx.x & 31;  // XCD = bh % 8
  const int qb = blockIdx.x >> 5;  // 32 q-blocks of 64 rows
  const f16* Q = qkv + (size_t)bh * BN * NHD;
  const f16* K = qkv + SLAB + (size_t)bh * BN * NHD;
  const f16* VT = qkv + 2 * SLAB + (size_t)bh * (size_t)NHD * BN;  // (hd, n)
  const int t = threadIdx.x, lane = t & 63, wave = t >> 6;
  const int grp = lane >> 4, qv = lane & 15;
  const int qrow = qb * 64 + wave * 16 + qv;

  const f16* Kb = K + (size_t)qv * NHD + grp * 8;   // + (k0+kt*16)*NHD
  const f16* Vb = VT + (size_t)qv * BN + grp * 4;   // + dt*16*BN + k0+kt*16

  f16x8 qf0 = *(const f16x8*)(Q + (size_t)qrow * NHD + grp * 8);
  f16x8 qf1 = *(const f16x8*)(Q + (size_t)qrow * NHD + 32 + grp * 8);

  const f32x4 zf = {0.f, 0.f, 0.f, 0.f};
  f32x4 acc[4];
#pragma unroll
  for (int i = 0; i < 4; i++) acc[i] = zf;
  float m = -1e30f, l = 0.f;

#pragma unroll 2
  for (int k0 = 0; k0 < BN; k0 += 32) {
    // K fragments (identical across the 4 waves; L2-resident)
    f16x8 kf[2][2];
#pragma unroll
    for (int kt = 0; kt < 2; kt++) {
      const f16* kr = Kb + (size_t)(k0 + kt * 16) * NHD;
      kf[kt][0] = *(const f16x8*)kr;
      kf[kt][1] = *(const f16x8*)(kr + 32);
    }
    // V^T fragments: A-operand of 16x16x16
    f16x4 vf[4][2];
#pragma unroll
    for (int dt = 0; dt < 4; dt++)
#pragma unroll
      for (int kt = 0; kt < 2; kt++)
        vf[dt][kt] = *(const f16x4*)(Vb + (size_t)dt * 16 * BN + k0 + kt * 16);

    // QK^T (S^T: row = key, col = q)
    f32x4 st[2];
#pragma unroll
    for (int kt = 0; kt < 2; kt++)
      st[kt] = mfma_k32(kf[kt][1], qf1, mfma_k32(kf[kt][0], qf0, zf));

    // online softmax for q = qv (replicated across the 4 lane-groups)
    float mt = st[0][0];
#pragma unroll
    for (int kt = 0; kt < 2; kt++)
#pragma unroll
      for (int i = 0; i < 4; i++) mt = fmaxf(mt, st[kt][i]);
    mt = fmaxf(mt, __shfl_xor(mt, 16));
    mt = fmaxf(mt, __shfl_xor(mt, 32));
    float newm = fmaxf(m, mt);
    float fsc = __expf(m - newm);
    f16x4 pb[2];
    float ps = 0.f;
#pragma unroll
    for (int kt = 0; kt < 2; kt++)
#pragma unroll
      for (int i = 0; i < 4; i++) {
        float e = __expf(st[kt][i] - newm);
        ps += e;
        pb[kt][i] = (f16)e;
      }
    ps += __shfl_xor(ps, 16);
    ps += __shfl_xor(ps, 32);
    l = l * fsc + ps;
    m = newm;
#pragma unroll
    for (int dt = 0; dt < 4; dt++) acc[dt] *= fsc;
    // PV: 16x16x16, A = V^T frag, B = P (direct from softmax layout)
#pragma unroll
    for (int dt = 0; dt < 4; dt++)
#pragma unroll
      for (int kt = 0; kt < 2; kt++)
        acc[dt] = mfma_k16(vf[dt][kt], pb[kt], acc[dt]);
  }

  // epilogue -> O (B,N,C) f16, vectorized 8B stores
  const int b = bh >> 3, h = bh & 7;
  float inv = 1.0f / l;
#pragma unroll
  for (int dt = 0; dt < 4; dt++) {
    f16x4 o = {(f16)(acc[dt][0] * inv), (f16)(acc[dt][1] * inv),
               (f16)(acc[dt][2] * inv), (f16)(acc[dt][3] * inv)};
    *(f16x4*)&O[((size_t)(b * BN + qrow)) * CC + h * NHD + dt * 16 + grp * 4] = o;
  }
}

// ---------------------------------------------------------------------------
// Output projection: out[m][d] = sum_c A[m][c] * Wproj[d][c] + bias[d]
// ---------------------------------------------------------------------------
__global__ __launch_bounds__(256)
void proj_gemm(const f16* __restrict__ A, const float* __restrict__ W,
               const float* __restrict__ bias, float* __restrict__ out) {
  __shared__ __align__(16) f16 As[128][40];
  __shared__ __align__(16) f16 Bs[128][40];
  const int t = threadIdx.x;
  const int lane = t & 63, wave = t >> 6;
  const int wr = wave >> 1, wc = wave & 1;
  const int mt = blockIdx.x >> 2, nt = blockIdx.x & 3;
  const int m0 = mt * 128, n0 = nt * 128;
  const int grp = lane >> 4, lid = lane & 15;

  const f32x4 zf = {0.f, 0.f, 0.f, 0.f};
  f32x4 acc[4][4];
#pragma unroll
  for (int i = 0; i < 4; i++)
#pragma unroll
    for (int j = 0; j < 4; j++) acc[i][j] = zf;

  const int r = t >> 1, hh = (t & 1) * 16;
  for (int k0 = 0; k0 < CC; k0 += 32) {
    const f16* sa = A + (size_t)(m0 + r) * CC + k0 + hh;
    f16x8 a0 = *(const f16x8*)sa;
    f16x8 a1 = *(const f16x8*)(sa + 8);
    *(f16x8*)&As[r][hh] = a0;
    *(f16x8*)&As[r][hh + 8] = a1;
    const float* sb = W + (size_t)(n0 + r) * CC + k0 + hh;
#pragma unroll
    for (int j = 0; j < 4; j++) {
      float4 vb = *(const float4*)(sb + 4 * j);
      f16x4 fb = {(f16)vb.x, (f16)vb.y, (f16)vb.z, (f16)vb.w};
      *(f16x4*)&Bs[r][hh + 4 * j] = fb;
    }
    __syncthreads();
    f16x8 af[4], bf[4];
#pragma unroll
    for (int mi = 0; mi < 4; mi++)
      af[mi] = *(const f16x8*)&As[wr * 64 + mi * 16 + lid][grp * 8];
#pragma unroll
    for (int ni = 0; ni < 4; ni++)
      bf[ni] = *(const f16x8*)&Bs[wc * 64 + ni * 16 + lid][grp * 8];
#pragma unroll
    for (int mi = 0; mi < 4; mi++)
#pragma unroll
      for (int ni = 0; ni < 4; ni++)
        acc[mi][ni] = mfma_k32(af[mi], bf[ni], acc[mi][ni]);
    __syncthreads();
  }
#pragma unroll
  for (int mi = 0; mi < 4; mi++) {
#pragma unroll
    for (int ni = 0; ni < 4; ni++) {
      int d = n0 + wc * 64 + ni * 16 + lid;
      float bv = bias[d];
#pragma unroll
      for (int i = 0; i < 4; i++) {
        int row = m0 + wr * 64 + mi * 16 + grp * 4 + i;
        out[(size_t)row * CC + d] = acc[mi][ni][i] + bv;
      }
    }
  }
}

extern "C" void kernel_launch(void* const* d_in, const int* in_sizes, int n_in,
                              void* d_out, int out_size, void* d_ws, size_t ws_size,
                              hipStream_t stream) {
  const float* x = (const float*)d_in[0];
  const float* w_qkv = (const float*)d_in[1];
  const float* w_proj = (const float*)d_in[2];
  const float* b_proj = (const float*)d_in[3];
  float* out = (float*)d_out;

  f16* qkv = (f16*)d_ws;                     // 3 slabs = 25.2 MB
  f16* Obuf = qkv + 3 * SLAB;                // 8.4 MB

  qkv_gemm<<<dim3(64 * 12), dim3(256), 0, stream>>>(x, w_qkv, qkv);
  attn<<<dim3(32 * 32), dim3(256), 0, stream>>>(qkv, Obuf);
  proj_gemm<<<dim3(64 * 4), dim3(256), 0, stream>>>(Obuf, w_proj, b_proj, out);
}

// Round 5
// 141.123 us; speedup vs baseline: 2.8088x; 2.8088x over previous
//
#include <hip/hip_runtime.h>

typedef _Float16 f16;
typedef _Float16 f16x4 __attribute__((ext_vector_type(4)));
typedef _Float16 f16x8 __attribute__((ext_vector_type(8)));
typedef float f32x4 __attribute__((ext_vector_type(4)));

static __device__ __forceinline__ f32x4 mfma_k32(f16x8 a, f16x8 b, f32x4 c) {
  return __builtin_amdgcn_mfma_f32_16x16x32_f16(a, b, c, 0, 0, 0);
}
static __device__ __forceinline__ f32x4 mfma_k16(f16x4 a, f16x4 b, f32x4 c) {
  return __builtin_amdgcn_mfma_f32_16x16x16f16(a, b, c, 0, 0, 0);
}

#define BN 2048    // sequence length
#define CC 512     // channels
#define NHD 64     // head dim
#define MROWS 8192 // B*N
#define SLAB ((size_t)32 * BN * NHD)  // one of Q/K/V: 4,194,304 f16
#define CH 64      // keys per LDS chunk

// ---------------------------------------------------------------------------
// QKV GEMM: C[m][d] = sum_k X[m][k] * Wqkv[d][k]
// M=8192, D=1536, K=512.
// Epilogue: Q (scaled 0.125) and K -> (b,h,n,hd); V -> TRANSPOSED (b,h,hd,n).
// ---------------------------------------------------------------------------
__global__ __launch_bounds__(256)
void qkv_gemm(const float* __restrict__ X, const float* __restrict__ W,
              f16* __restrict__ qkv) {
  __shared__ __align__(16) f16 As[128][40];
  __shared__ __align__(16) f16 Bs[128][40];
  const int t = threadIdx.x;
  const int lane = t & 63, wave = t >> 6;
  const int wr = wave >> 1, wc = wave & 1;
  const int mt = blockIdx.x / 12, nt = blockIdx.x % 12;
  const int m0 = mt * 128, n0 = nt * 128;
  const int grp = lane >> 4, lid = lane & 15;

  const f32x4 zf = {0.f, 0.f, 0.f, 0.f};
  f32x4 acc[4][4];
#pragma unroll
  for (int i = 0; i < 4; i++)
#pragma unroll
    for (int j = 0; j < 4; j++) acc[i][j] = zf;

  const int r = t >> 1, hh = (t & 1) * 16;
  for (int k0 = 0; k0 < CC; k0 += 32) {
    const float* sa = X + (size_t)(m0 + r) * CC + k0 + hh;
    const float* sb = W + (size_t)(n0 + r) * CC + k0 + hh;
#pragma unroll
    for (int j = 0; j < 4; j++) {
      float4 va = *(const float4*)(sa + 4 * j);
      float4 vb = *(const float4*)(sb + 4 * j);
      f16x4 fa = {(f16)va.x, (f16)va.y, (f16)va.z, (f16)va.w};
      f16x4 fb = {(f16)vb.x, (f16)vb.y, (f16)vb.z, (f16)vb.w};
      *(f16x4*)&As[r][hh + 4 * j] = fa;
      *(f16x4*)&Bs[r][hh + 4 * j] = fb;
    }
    __syncthreads();
    f16x8 af[4], bf[4];
#pragma unroll
    for (int mi = 0; mi < 4; mi++)
      af[mi] = *(const f16x8*)&As[wr * 64 + mi * 16 + lid][grp * 8];
#pragma unroll
    for (int ni = 0; ni < 4; ni++)
      bf[ni] = *(const f16x8*)&Bs[wc * 64 + ni * 16 + lid][grp * 8];
#pragma unroll
    for (int mi = 0; mi < 4; mi++)
#pragma unroll
      for (int ni = 0; ni < 4; ni++)
        acc[mi][ni] = mfma_k32(af[mi], bf[ni], acc[mi][ni]);
    __syncthreads();
  }
  // epilogue
#pragma unroll
  for (int ni = 0; ni < 4; ni++) {
    int d = n0 + wc * 64 + ni * 16 + lid;
    int s = d >> 9;
    int h = (d & 511) >> 6;
    int hd = d & 63;
    if (s == 2) {
      // V transposed: vT[((b*8+h)*64+hd)*2048 + n], vectorized 4-row store
#pragma unroll
      for (int mi = 0; mi < 4; mi++) {
        int row0 = m0 + wr * 64 + mi * 16 + grp * 4;
        int b = row0 >> 11, n = row0 & 2047;
        f16x4 pk = {(f16)acc[mi][ni][0], (f16)acc[mi][ni][1],
                    (f16)acc[mi][ni][2], (f16)acc[mi][ni][3]};
        *(f16x4*)&qkv[2 * SLAB + ((size_t)((b * 8 + h) * 64 + hd)) * BN + n] = pk;
      }
    } else {
      float scale = (s == 0) ? 0.125f : 1.0f;
#pragma unroll
      for (int mi = 0; mi < 4; mi++) {
#pragma unroll
        for (int i = 0; i < 4; i++) {
          int row = m0 + wr * 64 + mi * 16 + grp * 4 + i;
          int b = row >> 11, n = row & 2047;
          qkv[(size_t)s * SLAB + (((size_t)(b * 8 + h) * BN + n)) * NHD + hd] =
              (f16)(acc[mi][ni][i] * scale);
        }
      }
    }
  }
}

// ---------------------------------------------------------------------------
// Flash attention, LDS-staged K and V^T (both identical across the block's 4
// waves -> 4x fewer global vmem instructions than reg-direct R4).
// Double-buffered 64-key chunks (2 x 16 KB), XOR-swizzled LDS (T2:
// byte ^= (row&7)<<4 kills the 16-way conflict of 128B-stride rows), ONE
// barrier per chunk; stage loads issued at iter top so L2 latency hides
// under compute (T14). Grid: bid = qb*32+bh -> head pinned to XCD bh%8
// (R3/R4 confirmed FETCH 12 MB). Softmax/PV body = R4's verified code:
// swapped QK^T, lane (qv,grp) holds S[key=kt*16+grp*4+i][q=qv], P feeds
// PV (16x16x16 B-operand) directly from registers.
// ---------------------------------------------------------------------------
__global__ __launch_bounds__(256)
void attn(const f16* __restrict__ qkv, f16* __restrict__ O) {
  __shared__ __align__(16) f16 Ks[2][CH * NHD];  // [chunk row][64 f16], swizzled
  __shared__ __align__(16) f16 Vs[2][NHD * CH];  // [hd row][64 keys], swizzled

  const int bh = blockIdx.x & 31;  // XCD = bh % 8
  const int qb = blockIdx.x >> 5;  // 32 q-blocks of 64 rows
  const f16* Q = qkv + (size_t)bh * BN * NHD;
  const f16* K = qkv + SLAB + (size_t)bh * BN * NHD;
  const f16* VT = qkv + 2 * SLAB + (size_t)bh * (size_t)NHD * BN;  // (hd, n)
  const int t = threadIdx.x, lane = t & 63, wave = t >> 6;
  const int grp = lane >> 4, qv = lane & 15;
  const int qrow = qb * 64 + wave * 16 + qv;
  const int xr = (qv & 7) << 4;  // read-side swizzle term

  // staging decomposition: 512 units of 16B; thread t owns units t and t+256.
  // unit u: row = u>>3 (0..63), colblock cb = u&7 (16B blocks of a 128B row).
  const int r0 = t >> 3, cb = t & 7;
  const int r1 = 32 + r0;
  const f16* kg0 = K + (size_t)r0 * NHD + cb * 8;
  const f16* kg1 = K + (size_t)r1 * NHD + cb * 8;
  const f16* vg0 = VT + (size_t)r0 * BN + cb * 8;
  const f16* vg1 = VT + (size_t)r1 * BN + cb * 8;
  const int w0 = (r0 * 128 + cb * 16) ^ ((r0 & 7) << 4);
  const int w1 = (r1 * 128 + cb * 16) ^ ((r1 & 7) << 4);

  f16x8 qf0 = *(const f16x8*)(Q + (size_t)qrow * NHD + grp * 8);
  f16x8 qf1 = *(const f16x8*)(Q + (size_t)qrow * NHD + 32 + grp * 8);

  const f32x4 zf = {0.f, 0.f, 0.f, 0.f};
  f32x4 acc[4];
#pragma unroll
  for (int i = 0; i < 4; i++) acc[i] = zf;
  float m = -1e30f, l = 0.f;

  // prologue: stage chunk 0 into buffer 0
  {
    f16x8 sk0 = *(const f16x8*)kg0;
    f16x8 sk1 = *(const f16x8*)kg1;
    f16x8 sv0 = *(const f16x8*)vg0;
    f16x8 sv1 = *(const f16x8*)vg1;
    *(f16x8*)((char*)Ks[0] + w0) = sk0;
    *(f16x8*)((char*)Ks[0] + w1) = sk1;
    *(f16x8*)((char*)Vs[0] + w0) = sv0;
    *(f16x8*)((char*)Vs[0] + w1) = sv1;
  }
  __syncthreads();

  int cur = 0;
  for (int c = 0; c < BN / CH; ++c) {
    // issue next-chunk global loads first (latency hides under compute)
    const int c1 = ((c + 1) & (BN / CH - 1)) * CH;
    f16x8 sk0 = *(const f16x8*)(kg0 + (size_t)c1 * NHD);
    f16x8 sk1 = *(const f16x8*)(kg1 + (size_t)c1 * NHD);
    f16x8 sv0 = *(const f16x8*)(vg0 + c1);
    f16x8 sv1 = *(const f16x8*)(vg1 + c1);

    const char* kb = (const char*)Ks[cur];
    const char* vb = (const char*)Vs[cur];
    // two 32-key halves (R4's verified softmax/PV body per half)
#pragma unroll
    for (int h = 0; h < 2; h++) {
      // K fragments from LDS (swizzled b128 reads)
      f16x8 kf[2][2];
#pragma unroll
      for (int kt = 0; kt < 2; kt++) {
        int row = h * 32 + kt * 16 + qv;
#pragma unroll
        for (int j = 0; j < 2; j++)
          kf[kt][j] = *(const f16x8*)(kb + ((row * 128 + (grp + j * 4) * 16) ^ xr));
      }
      // V^T fragments from LDS (swizzled b64 reads)
      f16x4 vf[4][2];
#pragma unroll
      for (int dt = 0; dt < 4; dt++) {
        int row = dt * 16 + qv;
#pragma unroll
        for (int kt = 0; kt < 2; kt++)
          vf[dt][kt] = *(const f16x4*)(vb + ((row * 128 + h * 64 + kt * 32 + grp * 8) ^ xr));
      }
      // QK^T (S^T: row = key, col = q)
      f32x4 st[2];
#pragma unroll
      for (int kt = 0; kt < 2; kt++)
        st[kt] = mfma_k32(kf[kt][1], qf1, mfma_k32(kf[kt][0], qf0, zf));
      // online softmax for q = qv (replicated across the 4 lane-groups)
      float mt = st[0][0];
#pragma unroll
      for (int kt = 0; kt < 2; kt++)
#pragma unroll
        for (int i = 0; i < 4; i++) mt = fmaxf(mt, st[kt][i]);
      mt = fmaxf(mt, __shfl_xor(mt, 16));
      mt = fmaxf(mt, __shfl_xor(mt, 32));
      float newm = fmaxf(m, mt);
      float fsc = __expf(m - newm);
      f16x4 pb[2];
      float ps = 0.f;
#pragma unroll
      for (int kt = 0; kt < 2; kt++)
#pragma unroll
        for (int i = 0; i < 4; i++) {
          float e = __expf(st[kt][i] - newm);
          ps += e;
          pb[kt][i] = (f16)e;
        }
      ps += __shfl_xor(ps, 16);
      ps += __shfl_xor(ps, 32);
      l = l * fsc + ps;
      m = newm;
#pragma unroll
      for (int dt = 0; dt < 4; dt++) acc[dt] *= fsc;
      // PV: 16x16x16, A = V^T frag, B = P (direct from softmax layout)
#pragma unroll
      for (int dt = 0; dt < 4; dt++)
#pragma unroll
        for (int kt = 0; kt < 2; kt++)
          acc[dt] = mfma_k16(vf[dt][kt], pb[kt], acc[dt]);
    }

    // write next chunk into the other buffer; single barrier per iteration
    // (reads of buf[cur^1] all completed before the PREVIOUS barrier)
    *(f16x8*)((char*)Ks[cur ^ 1] + w0) = sk0;
    *(f16x8*)((char*)Ks[cur ^ 1] + w1) = sk1;
    *(f16x8*)((char*)Vs[cur ^ 1] + w0) = sv0;
    *(f16x8*)((char*)Vs[cur ^ 1] + w1) = sv1;
    __syncthreads();
    cur ^= 1;
  }

  // epilogue -> O (B,N,C) f16, vectorized 8B stores
  const int b = bh >> 3, h = bh & 7;
  float inv = 1.0f / l;
#pragma unroll
  for (int dt = 0; dt < 4; dt++) {
    f16x4 o = {(f16)(acc[dt][0] * inv), (f16)(acc[dt][1] * inv),
               (f16)(acc[dt][2] * inv), (f16)(acc[dt][3] * inv)};
    *(f16x4*)&O[((size_t)(b * BN + qrow)) * CC + h * NHD + dt * 16 + grp * 4] = o;
  }
}

// ---------------------------------------------------------------------------
// Output projection: out[m][d] = sum_c A[m][c] * Wproj[d][c] + bias[d]
// ---------------------------------------------------------------------------
__global__ __launch_bounds__(256)
void proj_gemm(const f16* __restrict__ A, const float* __restrict__ W,
               const float* __restrict__ bias, float* __restrict__ out) {
  __shared__ __align__(16) f16 As[128][40];
  __shared__ __align__(16) f16 Bs[128][40];
  const int t = threadIdx.x;
  const int lane = t & 63, wave = t >> 6;
  const int wr = wave >> 1, wc = wave & 1;
  const int mt = blockIdx.x >> 2, nt = blockIdx.x & 3;
  const int m0 = mt * 128, n0 = nt * 128;
  const int grp = lane >> 4, lid = lane & 15;

  const f32x4 zf = {0.f, 0.f, 0.f, 0.f};
  f32x4 acc[4][4];
#pragma unroll
  for (int i = 0; i < 4; i++)
#pragma unroll
    for (int j = 0; j < 4; j++) acc[i][j] = zf;

  const int r = t >> 1, hh = (t & 1) * 16;
  for (int k0 = 0; k0 < CC; k0 += 32) {
    const f16* sa = A + (size_t)(m0 + r) * CC + k0 + hh;
    f16x8 a0 = *(const f16x8*)sa;
    f16x8 a1 = *(const f16x8*)(sa + 8);
    *(f16x8*)&As[r][hh] = a0;
    *(f16x8*)&As[r][hh + 8] = a1;
    const float* sb = W + (size_t)(n0 + r) * CC + k0 + hh;
#pragma unroll
    for (int j = 0; j < 4; j++) {
      float4 vb = *(const float4*)(sb + 4 * j);
      f16x4 fb = {(f16)vb.x, (f16)vb.y, (f16)vb.z, (f16)vb.w};
      *(f16x4*)&Bs[r][hh + 4 * j] = fb;
    }
    __syncthreads();
    f16x8 af[4], bf[4];
#pragma unroll
    for (int mi = 0; mi < 4; mi++)
      af[mi] = *(const f16x8*)&As[wr * 64 + mi * 16 + lid][grp * 8];
#pragma unroll
    for (int ni = 0; ni < 4; ni++)
      bf[ni] = *(const f16x8*)&Bs[wc * 64 + ni * 16 + lid][grp * 8];
#pragma unroll
    for (int mi = 0; mi < 4; mi++)
#pragma unroll
      for (int ni = 0; ni < 4; ni++)
        acc[mi][ni] = mfma_k32(af[mi], bf[ni], acc[mi][ni]);
    __syncthreads();
  }
#pragma unroll
  for (int mi = 0; mi < 4; mi++) {
#pragma unroll
    for (int ni = 0; ni < 4; ni++) {
      int d = n0 + wc * 64 + ni * 16 + lid;
      float bv = bias[d];
#pragma unroll
      for (int i = 0; i < 4; i++) {
        int row = m0 + wr * 64 + mi * 16 + grp * 4 + i;
        out[(size_t)row * CC + d] = acc[mi][ni][i] + bv;
      }
    }
  }
}

extern "C" void kernel_launch(void* const* d_in, const int* in_sizes, int n_in,
                              void* d_out, int out_size, void* d_ws, size_t ws_size,
                              hipStream_t stream) {
  const float* x = (const float*)d_in[0];
  const float* w_qkv = (const float*)d_in[1];
  const float* w_proj = (const float*)d_in[2];
  const float* b_proj = (const float*)d_in[3];
  float* out = (float*)d_out;

  f16* qkv = (f16*)d_ws;                     // 3 slabs = 25.2 MB
  f16* Obuf = qkv + 3 * SLAB;                // 8.4 MB

  qkv_gemm<<<dim3(64 * 12), dim3(256), 0, stream>>>(x, w_qkv, qkv);
  attn<<<dim3(32 * 32), dim3(256), 0, stream>>>(qkv, Obuf);
  proj_gemm<<<dim3(64 * 4), dim3(256), 0, stream>>>(Obuf, w_proj, b_proj, out);
}